// Round 8
// baseline (632.841 us; speedup 1.0000x reference)
//
#include <hip/hip_runtime.h>
#include <math.h>

#define NE 8
#define NH 2048
#define NI 1024
#define NT 512
#define NTOPK 2
#define NR 16
#define NGROUP 64
#define NPAIR (NT*NTOPK)   // 1024

typedef short bf16x8 __attribute__((ext_vector_type(8)));
typedef float f32x16 __attribute__((ext_vector_type(16)));
typedef unsigned int u32;

#define MFMA32 __builtin_amdgcn_mfma_f32_32x32x16_bf16

__device__ const float NF4_TAB[16] = {
    -1.0f, -0.6961928009986877f, -0.5250730514526367f, -0.39491748809814453f,
    -0.28444138169288635f, -0.18477343022823334f, -0.09105003625154495f, 0.0f,
    0.07958029955625534f, 0.16093020141124725f, 0.24611230194568634f,
    0.33791524171829224f, 0.44070982933044434f, 0.5626170039176941f,
    0.7229568362236328f, 1.0f};

// ---------------- workspace layout (bytes) ----------------
#define OFF_EXPOFF 0         // int[16]
#define OFF_TOK    256       // int[1024]
#define OFF_EXP    4352      // int[1024]
#define OFF_W      8448      // float[1024]
#define OFF_XAG    12544     // ushort[1024*16] bf16
#define OFF_XAU    45312     // ushort[1024*16]
#define OFF_HA     78080     // ushort[1024*16]
#define OFF_XCT    131072    // ushort[NH/8][NPAIR][8] transposed compact x (4 MB)
#define OFF_GU     4325376   // ushort[2*1024*1024] gate|up results (4 MB)
#define OFF_HT     8519680   // ushort[NI/8][NPAIR][8] transposed h (2 MB)
#define OFF_WTG    10616832  // ushort[NE][NH/8][NI][8] dequant gate (32 MB)
#define OFF_WTU    44171264  // ushort[NE][NH/8][NI][8] dequant up   (32 MB)
#define OFF_WTD    77725696  // ushort[NE][NI/8][NH][8] dequant down (32 MB)
                             // end = 111280128 (< 256 MiB workspace, evidenced
                             // by the harness's 256 MiB poison fills)

__device__ inline u32 f2bf(float f) {
    return (__float_as_uint(f) + 0x8000u) >> 16;
}
__device__ inline u32 bfpack2(float a, float b) {
    return ((__float_as_uint(a) + 0x8000u) >> 16) |
           ((__float_as_uint(b) + 0x8000u) & 0xFFFF0000u);
}
__device__ inline bf16x8 asbf(uint4 w) {
    union { uint4 u; bf16x8 b; } c; c.u = w; return c.b;
}
__device__ inline bf16x8 bfzero() { return asbf(make_uint4(0,0,0,0)); }
__device__ inline float bf2f(u32 v) { return __uint_as_float(v << 16); }

// -------- kernel 0: dequantize NF4 -> bf16, chunk-transposed (3 mats+route) --
// in: [e][kp (K2)][col (N)] int32 (one useful byte = 2 codes).
// out: [e][K/8][N][8] bf16, PRE-SCALED (w = tab_f32 * scale, single bf16
// rounding -- same error bound as the old lut-bf16 * f32-scale path).
// One 32kp x 128col tile per block: uint4 global loads, dequant+scale in
// VALU (float2 LUT gather), uint4 LDS tile, uint4 stores.
// A 32-kp tile spans exactly one 64-elem scale group (NGROUP=64 = 32 kp).
// z<16: gate(even)/up(odd); 16<=z<24: down; z==24: routing compaction.
__global__ __launch_bounds__(256) void k_deq(const u32* __restrict__ gin,
                                             const u32* __restrict__ uin,
                                             const u32* __restrict__ din,
                                             const float* __restrict__ gsc,
                                             const float* __restrict__ usc,
                                             const float* __restrict__ dsc,
                                             unsigned short* __restrict__ wg,
                                             unsigned short* __restrict__ wu,
                                             unsigned short* __restrict__ wd,
                                             const int* __restrict__ idx,
                                             const float* __restrict__ w,
                                             int* expert_off, int* ptok,
                                             int* pexp, float* pw) {
    __shared__ float2 lutf[256];         // 2 KB: {tab[lo], tab[hi]} per byte
    __shared__ uint4 tile4[32][32];      // 16 KB: [kp][c16] = 4 cols' pairs
    __shared__ int cnt[NE], off2[NE + 1], cur[NE];
    int tid = threadIdx.x;
    int z = blockIdx.z;

    if (z == 24) {                       // routing compaction (1 block)
        if (blockIdx.x || blockIdx.y) return;
        if (tid < NE) cnt[tid] = 0;
        __syncthreads();
        int e4[4]; float w4[4];
        #pragma unroll
        for (int i = 0; i < 4; ++i) {
            int pr = tid * 4 + i;
            e4[i] = idx[pr]; w4[i] = w[pr];
            atomicAdd(&cnt[e4[i]], 1);
        }
        __syncthreads();
        if (tid == 0) {
            off2[0] = 0;
            for (int i = 0; i < NE; i++) off2[i + 1] = off2[i] + cnt[i];
        }
        __syncthreads();
        if (tid < NE) cur[tid] = off2[tid];
        __syncthreads();
        #pragma unroll
        for (int i = 0; i < 4; ++i) {
            int pr = tid * 4 + i;
            int pos = atomicAdd(&cur[e4[i]], 1);
            ptok[pos] = pr >> 1; pexp[pos] = e4[i]; pw[pos] = w4[i];
        }
        if (tid <= NE) expert_off[tid] = off2[tid];
        return;
    }

    const u32* in; const float* sc; unsigned short* out; int K2, N, e;
    if (z < 2 * NE) {
        e = z >> 1;
        in = (z & 1) ? uin : gin; sc = (z & 1) ? usc : gsc;
        out = (z & 1) ? wu : wg;
        K2 = NH / 2; N = NI;
        if ((int)blockIdx.x >= N / 128) return;
    } else {
        e = z - 2 * NE;
        in = din; sc = dsc; out = wd;
        K2 = NI / 2; N = NH;
        if ((int)blockIdx.y >= K2 / 32) return;
    }
    int kp0 = blockIdx.y * 32, c0 = blockIdx.x * 128;

    lutf[tid] = make_float2(NF4_TAB[tid & 15], NF4_TAB[(tid >> 4) & 15]);
    __syncthreads();

    // phase A: read 32kp x 128col int32, dequant+scale -> LDS uint4 tile
    int r8 = tid >> 5, c16 = tid & 31;
    const u32* ip = in + (size_t)e * K2 * N + (size_t)kp0 * N + c0;
    float4 scl = *(const float4*)(sc + (size_t)e * (K2 / 32) * N
                                  + (size_t)blockIdx.y * N + c0 + c16 * 4);
    const float* sp = &scl.x;
    #pragma unroll
    for (int pass = 0; pass < 4; ++pass) {
        int r = pass * 8 + r8;
        uint4 v = *(const uint4*)(ip + (size_t)r * N + c16 * 4);
        const u32* vp = &v.x;
        uint4 ow; u32* owp = &ow.x;
        #pragma unroll
        for (int i = 0; i < 4; ++i) {
            float2 tv = lutf[vp[i] & 255];
            owp[i] = bfpack2(tv.x * sp[i], tv.y * sp[i]);
        }
        tile4[r][c16] = ow;              // b128 write, lanes sequential
    }
    __syncthreads();

    // phase B: per col, 4 chunks of 4 kp-pair dwords -> uint4 stores
    int col = tid & 127, ch2 = tid >> 7;
    const u32* t32 = (const u32*)&tile4[0][0];   // [kp*128 + col]
    #pragma unroll
    for (int j = 0; j < 4; ++j) {
        int cc = ch2 * 4 + j;            // local chunk 0..7
        uint4 ow;
        ow.x = t32[(cc * 4 + 0) * 128 + col];
        ow.y = t32[(cc * 4 + 1) * 128 + col];
        ow.z = t32[(cc * 4 + 2) * 128 + col];
        ow.w = t32[(cc * 4 + 3) * 128 + col];
        *(uint4*)(out + (((size_t)e * (K2 / 4) + (kp0 >> 2) + cc) * N
                         + (c0 + col)) * 8) = ow;
    }
}

// -------- kernel 2: x gather/transpose + xA products --------
__global__ __launch_bounds__(256) void k_xA(const float* __restrict__ x,
                                            const float* __restrict__ gA,
                                            const float* __restrict__ uA,
                                            const int* __restrict__ ptok,
                                            const int* __restrict__ pexp,
                                            unsigned short* __restrict__ xcT,
                                            unsigned short* __restrict__ xAg,
                                            unsigned short* __restrict__ xAu) {
    __shared__ float xs[NH];             // 8 KB
    __shared__ float red[2][64][17];     // padded, ~8.7 KB
    int p = blockIdx.x;
    int t = ptok[p], e = pexp[p];
    int tid = threadIdx.x;

    int k = tid * 8;
    const float* xr = x + (size_t)t * NH + k;
    float4 v0 = *(const float4*)xr;
    float4 v1 = *(const float4*)(xr + 4);
    uint4 w;
    w.x = bfpack2(v0.x, v0.y); w.y = bfpack2(v0.z, v0.w);
    w.z = bfpack2(v1.x, v1.y); w.w = bfpack2(v1.z, v1.w);
    *(uint4*)(xcT + ((size_t)(k >> 3) * NPAIR + p) * 8) = w;
    *(float4*)(xs + k) = v0;
    *(float4*)(xs + k + 4) = v1;
    __syncthreads();

    int ch = tid & 63, rg = tid >> 6;    // r = rg*4 + i
    const float* gAr = gA + (size_t)e * NH * NR + rg * 4;
    const float* uAr = uA + (size_t)e * NH * NR + rg * 4;
    float4 sg = make_float4(0.f, 0.f, 0.f, 0.f);
    float4 su = make_float4(0.f, 0.f, 0.f, 0.f);
    #pragma unroll 4
    for (int jj = 0; jj < NH / 64; ++jj) {
        int j = jj * 64 + ch;
        float xv = xs[j];
        float4 ga = *(const float4*)(gAr + (size_t)j * NR);
        float4 ua = *(const float4*)(uAr + (size_t)j * NR);
        sg.x += xv * ga.x; sg.y += xv * ga.y; sg.z += xv * ga.z; sg.w += xv * ga.w;
        su.x += xv * ua.x; su.y += xv * ua.y; su.z += xv * ua.z; su.w += xv * ua.w;
    }
    red[0][ch][rg * 4 + 0] = sg.x; red[0][ch][rg * 4 + 1] = sg.y;
    red[0][ch][rg * 4 + 2] = sg.z; red[0][ch][rg * 4 + 3] = sg.w;
    red[1][ch][rg * 4 + 0] = su.x; red[1][ch][rg * 4 + 1] = su.y;
    red[1][ch][rg * 4 + 2] = su.z; red[1][ch][rg * 4 + 3] = su.w;
    __syncthreads();
    for (int st = 32; st >= 1; st >>= 1) {
        if (ch < st) {
            #pragma unroll
            for (int i = 0; i < 4; ++i) {
                red[0][ch][rg * 4 + i] += red[0][ch + st][rg * 4 + i];
                red[1][ch][rg * 4 + i] += red[1][ch + st][rg * 4 + i];
            }
        }
        __syncthreads();
    }
    if (tid < 16)
        xAg[p * NR + tid] = (unsigned short)f2bf(red[0][0][tid]);
    else if (tid < 32)
        xAu[p * NR + (tid - 16)] = (unsigned short)f2bf(red[1][0][tid - 16]);
}

// -------- kernel 4: gate OR up grouped GEMM on pre-dequantized bf16 --------
// 1 wave/block, 32x32 tile. Inner step = 4 A-loads + 4 W-loads + 4 MFMA
// direct-accumulate. NO LDS, no LUT, no scales (folded into W), no barriers.
// Static-named double buffers, unrolled x2; compiler inserts counted vmcnt.
__global__ __launch_bounds__(64, 3) void k_gu(
    const unsigned short* __restrict__ xcT,
    const unsigned short* __restrict__ wg,
    const unsigned short* __restrict__ wu,
    const float* __restrict__ gB, const float* __restrict__ uB,
    const unsigned short* __restrict__ xAg, const unsigned short* __restrict__ xAu,
    const int* __restrict__ expert_off,
    unsigned short* __restrict__ gu)
{
    int lane = threadIdx.x;
    int q = lane >> 5, cw = lane & 31;

    int e = blockIdx.x;
    int c0 = blockIdx.y * 32;
    int mat = blockIdx.z & 1;
    int rt = blockIdx.z >> 1;                 // row-tile 0..3
    const float* Bp = mat ? uB : gB;
    const unsigned short* xA = mat ? xAu : xAg;

    int off = expert_off[e];
    int cnt = expert_off[e + 1] - off;
    int colg = c0 + cw;

    // per-lane W base: chunk = s*8 + q*4 + ks over [e][NH/8][NI][8]
    const unsigned short* wbase = (mat ? wu : wg)
        + (size_t)e * (NH / 8) * (size_t)NI * 8
        + ((size_t)(q << 2) * NI + colg) * 8;

    const int NS = NH / 64;                   // 32 K-steps (even)
    for (int s0 = rt * 32; s0 < cnt; s0 += 128) {
        int rr = s0 + cw; if (rr > cnt - 1) rr = cnt - 1;
        int prow = off + rr;

        auto loadW = [&](bf16x8* d, int s) {  // 4 coalesced dwordx4 W loads
            #pragma unroll
            for (int ks = 0; ks < 4; ++ks)
                d[ks] = *(const bf16x8*)(wbase +
                            (size_t)((s << 3) + ks) * NI * 8);
        };
        auto loadA = [&](bf16x8* d, int s) {  // 4 coalesced dwordx4 A loads
            #pragma unroll
            for (int ks = 0; ks < 4; ++ks)
                d[ks] = *(const bf16x8*)(xcT +
                            ((size_t)((s << 3) + (q << 2) + ks) * NPAIR + prow) * 8);
        };

        bf16x8 Aa[4], Ab[4], Wa[4], Wb[4];    // static-indexed (unrolled ks)
        f32x16 acc;
        #pragma unroll
        for (int i = 0; i < 16; ++i) acc[i] = 0.f;

        auto compute = [&](const bf16x8* Ar, const bf16x8* Wr) {
            #pragma unroll
            for (int ks = 0; ks < 4; ++ks)
                acc = MFMA32(Ar[ks], Wr[ks], acc, 0, 0, 0);
        };

        loadW(Wa, 0); loadA(Aa, 0);
        loadW(Wb, 1); loadA(Ab, 1);
        for (int s = 0; s < NS; s += 2) {
            compute(Aa, Wa);
            if (s + 2 < NS) { loadW(Wa, s + 2); loadA(Aa, s + 2); }
            compute(Ab, Wb);
            if (s + 3 < NS) { loadW(Wb, s + 3); loadA(Ab, s + 3); }
        }

        // LoRA extension: += (x.A) . B  (K = 16)
        {
            bf16x8 la = bfzero();
            if (s0 + cw < cnt)
                la = *(const bf16x8*)(xA + (size_t)(off + s0 + cw) * NR + (q << 3));
            const float* Bq = Bp + ((size_t)e * NR + (q << 3)) * NI + colg;
            uint4 w4; u32* wp = &w4.x;
            #pragma unroll
            for (int i = 0; i < 4; ++i)
                wp[i] = bfpack2(Bq[(2 * i) * NI], Bq[(2 * i + 1) * NI]);
            acc = MFMA32(la, asbf(w4), acc, 0, 0, 0);
        }
        // epilogue: store bf16 tile. C row = (reg&3) + 8*(reg>>2) + 4*q
        unsigned short* outb = gu + (size_t)mat * NPAIR * NI;
        #pragma unroll
        for (int reg = 0; reg < 16; ++reg) {
            int rloc = (reg & 3) + 8 * (reg >> 2) + (q << 2);
            if (s0 + rloc < cnt)
                outb[(size_t)(off + s0 + rloc) * NI + colg] =
                    (unsigned short)f2bf(acc[reg]);
        }
    }
}

// -------- kernel 5: h = silu(gate)*up -> hT, + hA = h . down_A (fused) ------
__global__ __launch_bounds__(256) void k_hsw(const unsigned short* __restrict__ gu,
                                             const float* __restrict__ dA,
                                             const int* __restrict__ pexp,
                                             unsigned short* __restrict__ hT,
                                             unsigned short* __restrict__ hA) {
    __shared__ float hs[NI];             // 4 KB
    __shared__ float red[64][17];        // padded, ~4.3 KB
    int p = blockIdx.x, e = pexp[p];
    int tid = threadIdx.x;

    int i = tid * 4;
    uint2 gv = *(const uint2*)(gu + (size_t)p * NI + i);
    uint2 uv = *(const uint2*)(gu + (size_t)NPAIR * NI + (size_t)p * NI + i);
    const u32* gp = &gv.x; const u32* up = &uv.x;
    uint2 hv; u32* hp = &hv.x;
    float4 h4;
    {
        float g0 = bf2f(gp[0] & 0xFFFFu), g1 = bf2f(gp[0] >> 16);
        float u0 = bf2f(up[0] & 0xFFFFu), u1 = bf2f(up[0] >> 16);
        h4.x = g0 * u0 / (1.f + __expf(-g0));
        h4.y = g1 * u1 / (1.f + __expf(-g1));
        hp[0] = bfpack2(h4.x, h4.y);
        float g2 = bf2f(gp[1] & 0xFFFFu), g3 = bf2f(gp[1] >> 16);
        float u2 = bf2f(up[1] & 0xFFFFu), u3 = bf2f(up[1] >> 16);
        h4.z = g2 * u2 / (1.f + __expf(-g2));
        h4.w = g3 * u3 / (1.f + __expf(-g3));
        hp[1] = bfpack2(h4.z, h4.w);
    }
    *(uint2*)(hT + ((size_t)(i >> 3) * NPAIR + p) * 8 + (i & 7)) = hv;
    *(float4*)(hs + i) = h4;
    __syncthreads();

    int ch = tid & 63, rg = tid >> 6;
    const float* dAr = dA + (size_t)e * NI * NR + rg * 4;
    float4 sv = make_float4(0.f, 0.f, 0.f, 0.f);
    #pragma unroll 4
    for (int jj = 0; jj < NI / 64; ++jj) {
        int j = jj * 64 + ch;
        float hvv = hs[j];
        float4 da = *(const float4*)(dAr + (size_t)j * NR);
        sv.x += hvv * da.x; sv.y += hvv * da.y;
        sv.z += hvv * da.z; sv.w += hvv * da.w;
    }
    red[ch][rg * 4 + 0] = sv.x; red[ch][rg * 4 + 1] = sv.y;
    red[ch][rg * 4 + 2] = sv.z; red[ch][rg * 4 + 3] = sv.w;
    __syncthreads();
    for (int st = 32; st >= 1; st >>= 1) {
        if (ch < st) {
            #pragma unroll
            for (int i2 = 0; i2 < 4; ++i2)
                red[ch][rg * 4 + i2] += red[ch + st][rg * 4 + i2];
        }
        __syncthreads();
    }
    if (tid < 16) hA[p * NR + tid] = (unsigned short)f2bf(red[0][tid]);
}

// -------- kernel 7: down GEMM on pre-dequantized bf16 + combine ----
__global__ __launch_bounds__(64, 3) void k_dn(
    const unsigned short* __restrict__ hT,
    const unsigned short* __restrict__ wd,
    const float* __restrict__ dB,
    const unsigned short* __restrict__ hA,
    const int* __restrict__ expert_off, const int* __restrict__ ptok,
    const float* __restrict__ pw,
    float* __restrict__ out)
{
    int lane = threadIdx.x;
    int q = lane >> 5, cw = lane & 31;

    int e = blockIdx.x;
    int c0 = blockIdx.y * 32;
    int rt = blockIdx.z;                      // 0..3

    int off = expert_off[e];
    int cnt = expert_off[e + 1] - off;
    int colg = c0 + cw;

    const unsigned short* wbase = wd
        + (size_t)e * (NI / 8) * (size_t)NH * 8
        + ((size_t)(q << 2) * NH + colg) * 8;

    const int NS = NI / 64;                   // 16 K-steps (even)
    for (int s0 = rt * 32; s0 < cnt; s0 += 128) {
        int rr = s0 + cw; if (rr > cnt - 1) rr = cnt - 1;
        int prow = off + rr;

        auto loadW = [&](bf16x8* d, int s) {
            #pragma unroll
            for (int ks = 0; ks < 4; ++ks)
                d[ks] = *(const bf16x8*)(wbase +
                            (size_t)((s << 3) + ks) * NH * 8);
        };
        auto loadA = [&](bf16x8* d, int s) {
            #pragma unroll
            for (int ks = 0; ks < 4; ++ks)
                d[ks] = *(const bf16x8*)(hT +
                            ((size_t)((s << 3) + (q << 2) + ks) * NPAIR + prow) * 8);
        };

        bf16x8 Aa[4], Ab[4], Wa[4], Wb[4];
        f32x16 acc;
        #pragma unroll
        for (int i = 0; i < 16; ++i) acc[i] = 0.f;

        auto compute = [&](const bf16x8* Ar, const bf16x8* Wr) {
            #pragma unroll
            for (int ks = 0; ks < 4; ++ks)
                acc = MFMA32(Ar[ks], Wr[ks], acc, 0, 0, 0);
        };

        loadW(Wa, 0); loadA(Aa, 0);
        loadW(Wb, 1); loadA(Ab, 1);
        for (int s = 0; s < NS; s += 2) {
            compute(Aa, Wa);
            if (s + 2 < NS) { loadW(Wa, s + 2); loadA(Aa, s + 2); }
            compute(Ab, Wb);
            if (s + 3 < NS) { loadW(Wb, s + 3); loadA(Ab, s + 3); }
        }

        // LoRA extension: += (h.down_A) . down_B (K = 16)
        {
            bf16x8 la = bfzero();
            if (s0 + cw < cnt)
                la = *(const bf16x8*)(hA + (size_t)(off + s0 + cw) * NR + (q << 3));
            const float* Bq = dB + ((size_t)e * NR + (q << 3)) * NH + colg;
            uint4 w4; u32* wp = &w4.x;
            #pragma unroll
            for (int i = 0; i < 4; ++i)
                wp[i] = bfpack2(Bq[(2 * i) * NH], Bq[(2 * i + 1) * NH]);
            acc = MFMA32(la, asbf(w4), acc, 0, 0, 0);
        }
        // epilogue: weighted atomic combine
        #pragma unroll
        for (int reg = 0; reg < 16; ++reg) {
            int rloc = (reg & 3) + 8 * (reg >> 2) + (q << 2);
            if (s0 + rloc < cnt) {
                int p = off + s0 + rloc;
                atomicAdd(&out[(size_t)ptok[p] * NH + colg], acc[reg] * pw[p]);
            }
        }
    }
}

extern "C" void kernel_launch(void* const* d_in, const int* in_sizes, int n_in,
                              void* d_out, int out_size, void* d_ws,
                              size_t ws_size, hipStream_t stream) {
    const float* x = (const float*)d_in[0];
    const int* topk_idx = (const int*)d_in[1];
    const float* topk_w = (const float*)d_in[2];
    const int* gate_packed = (const int*)d_in[3];
    const float* gate_scales = (const float*)d_in[4];
    const int* up_packed = (const int*)d_in[5];
    const float* up_scales = (const float*)d_in[6];
    const int* down_packed = (const int*)d_in[7];
    const float* down_scales = (const float*)d_in[8];
    const float* gate_A = (const float*)d_in[9];
    const float* gate_B = (const float*)d_in[10];
    const float* up_A = (const float*)d_in[11];
    const float* up_B = (const float*)d_in[12];
    const float* down_A = (const float*)d_in[13];
    const float* down_B = (const float*)d_in[14];
    float* out = (float*)d_out;

    char* ws = (char*)d_ws;
    int* expert_off = (int*)(ws + OFF_EXPOFF);
    int* ptok = (int*)(ws + OFF_TOK);
    int* pexp = (int*)(ws + OFF_EXP);
    float* pw = (float*)(ws + OFF_W);
    unsigned short* xAg = (unsigned short*)(ws + OFF_XAG);
    unsigned short* xAu = (unsigned short*)(ws + OFF_XAU);
    unsigned short* hA = (unsigned short*)(ws + OFF_HA);
    unsigned short* xcT = (unsigned short*)(ws + OFF_XCT);
    unsigned short* gu = (unsigned short*)(ws + OFF_GU);
    unsigned short* hT = (unsigned short*)(ws + OFF_HT);
    unsigned short* wtg = (unsigned short*)(ws + OFF_WTG);
    unsigned short* wtu = (unsigned short*)(ws + OFF_WTU);
    unsigned short* wtd = (unsigned short*)(ws + OFF_WTD);

    hipMemsetAsync(d_out, 0, (size_t)NT * NH * sizeof(float), stream);

    // dequant prepass (all 3 matrices, pre-scaled bf16) + routing, one launch
    k_deq<<<dim3(16, 32, 25), 256, 0, stream>>>(
        (const u32*)gate_packed, (const u32*)up_packed, (const u32*)down_packed,
        gate_scales, up_scales, down_scales, wtg, wtu, wtd,
        topk_idx, topk_w, expert_off, ptok, pexp, pw);

    k_xA<<<NPAIR, 256, 0, stream>>>(x, gate_A, up_A, ptok, pexp, xcT, xAg, xAu);
    k_gu<<<dim3(NE, NI / 32, 8), 64, 0, stream>>>(
        xcT, wtg, wtu, gate_B, up_B, xAg, xAu, expert_off, gu);
    k_hsw<<<NPAIR, 256, 0, stream>>>(gu, down_A, pexp, hT, hA);
    k_dn<<<dim3(NE, NH / 32, 4), 64, 0, stream>>>(
        hT, wtd, down_B, hA, expert_off, ptok, pw, out);
}

// Round 9
// 262.669 us; speedup vs baseline: 2.4093x; 2.4093x over previous
//
#include <hip/hip_runtime.h>
#include <math.h>

#define NE 8
#define NH 2048
#define NI 1024
#define NT 512
#define NTOPK 2
#define NR 16
#define NGROUP 64
#define NPAIR (NT*NTOPK)   // 1024

// compact code buffers: [e][col][kp] bytes, padded col stride (multiple of 16,
// NOT a power of two -> avoids L2 channel camping on the lane stride)
#define SPG 1040             // gate/up: K2 = NH/2 = 1024 -> stride 1040
#define SPD 528              // down:    K2 = NI/2 = 512  -> stride 528

typedef short bf16x8 __attribute__((ext_vector_type(8)));
typedef float f32x16 __attribute__((ext_vector_type(16)));
typedef unsigned int u32;

#define MFMA32 __builtin_amdgcn_mfma_f32_32x32x16_bf16

__device__ const float NF4_TAB[16] = {
    -1.0f, -0.6961928009986877f, -0.5250730514526367f, -0.39491748809814453f,
    -0.28444138169288635f, -0.18477343022823334f, -0.09105003625154495f, 0.0f,
    0.07958029955625534f, 0.16093020141124725f, 0.24611230194568634f,
    0.33791524171829224f, 0.44070982933044434f, 0.5626170039176941f,
    0.7229568362236328f, 1.0f};

// ---------------- workspace layout (bytes) ----------------
#define OFF_EXPOFF 0         // int[16]
#define OFF_TOK    256       // int[1024]
#define OFF_EXP    4352      // int[1024]
#define OFF_W      8448      // float[1024]
#define OFF_XAG    12544     // ushort[1024*16] bf16
#define OFF_XAU    45312     // ushort[1024*16]
#define OFF_HA     78080     // ushort[1024*16]
#define OFF_XCT    131072    // ushort[NH/8][NPAIR][8] transposed compact x (4 MB)
#define OFF_GU     4325376   // ushort[2*1024*1024] gate|up results (4 MB)
#define OFF_HBUF   8519680   // ushort[NPAIR*NI] row-major h (2 MB)
#define OFF_HT     10616832  // ushort[NI/8][NPAIR][8] transposed h (2 MB)
#define OFF_CG     12713984  // uchar[NE][NI][SPG] compact gate codes (8.5 MB)
#define OFF_CU     21233664  // uchar[NE][NI][SPG] compact up codes
#define OFF_CD     29753344  // uchar[NE][NH][SPD] compact down codes (8.65 MB)
                             // end = 38404096

__device__ inline u32 f2bf(float f) {
    return (__float_as_uint(f) + 0x8000u) >> 16;
}
__device__ inline u32 bfpack2(float a, float b) {
    return ((__float_as_uint(a) + 0x8000u) >> 16) |
           ((__float_as_uint(b) + 0x8000u) & 0xFFFF0000u);
}
__device__ inline bf16x8 asbf(uint4 w) {
    union { uint4 u; bf16x8 b; } c; c.u = w; return c.b;
}
__device__ inline bf16x8 bfzero() { return asbf(make_uint4(0,0,0,0)); }
__device__ inline float bf2f(u32 v) { return __uint_as_float(v << 16); }

// async global->LDS: per-lane global addr, LDS dest = wave-uniform base + lane*16
__device__ __forceinline__ void stage16(const void* g, void* l) {
    __builtin_amdgcn_global_load_lds(
        (const __attribute__((address_space(1))) u32*)g,
        (__attribute__((address_space(3))) u32*)l, 16, 0, 0);
}
#define WAITV0()  asm volatile("s_waitcnt vmcnt(0)" ::: "memory")

// -------- kernel 0: compact int32 codes -> transposed uint8 (3 mats + route) -
// in: [e][kp (K2)][col (N)] int32 (one useful byte each)
// out: [e][col][kp] uint8, col stride SP.
// 32 kp x 128 col tiles: dwordx4 loads (4 cols/lane), u32-packed LDS tile,
// dwordx4 stores (32B contiguous per col).
// z<16: gate(even)/up(odd); 16<=z<24: down; z==24: routing compaction.
__global__ __launch_bounds__(256) void k_cmp3(const u32* __restrict__ gin,
                                              const u32* __restrict__ uin,
                                              const u32* __restrict__ din,
                                              unsigned char* __restrict__ cg,
                                              unsigned char* __restrict__ cu,
                                              unsigned char* __restrict__ cd,
                                              const int* __restrict__ idx,
                                              const float* __restrict__ w,
                                              int* expert_off, int* ptok,
                                              int* pexp, float* pw) {
    __shared__ u32 tile32[32][33];
    __shared__ int cnt[NE], off2[NE + 1], cur[NE];
    int tid = threadIdx.x;
    int z = blockIdx.z;

    if (z == 24) {                            // routing compaction (1 block)
        if (blockIdx.x || blockIdx.y) return;
        if (tid < NE) cnt[tid] = 0;
        __syncthreads();
        int e4[4]; float w4[4];
        #pragma unroll
        for (int i = 0; i < 4; ++i) {
            int pr = tid * 4 + i;
            e4[i] = idx[pr]; w4[i] = w[pr];
            atomicAdd(&cnt[e4[i]], 1);
        }
        __syncthreads();
        if (tid == 0) {
            off2[0] = 0;
            for (int i = 0; i < NE; i++) off2[i + 1] = off2[i] + cnt[i];
        }
        __syncthreads();
        if (tid < NE) cur[tid] = off2[tid];
        __syncthreads();
        #pragma unroll
        for (int i = 0; i < 4; ++i) {
            int pr = tid * 4 + i;
            int pos = atomicAdd(&cur[e4[i]], 1);
            ptok[pos] = pr >> 1; pexp[pos] = e4[i]; pw[pos] = w4[i];
        }
        if (tid <= NE) expert_off[tid] = off2[tid];
        return;
    }

    const u32* in; unsigned char* out; int K2, N, SP, e;
    if (z < 2 * NE) {
        e = z >> 1;
        in = (z & 1) ? uin : gin; out = (z & 1) ? cu : cg;
        K2 = NH / 2; N = NI; SP = SPG;
        if ((int)blockIdx.x >= N / 128) return;
    } else {
        e = z - 2 * NE;
        in = din; out = cd;
        K2 = NI / 2; N = NH; SP = SPD;
        if ((int)blockIdx.y >= K2 / 32) return;
    }
    int kp0 = blockIdx.y * 32, c0 = blockIdx.x * 128;

    // phase A: 32 kp x 128 col -> LDS, u32-packed (4 cols per dword)
    int c16 = tid & 31, rr = tid >> 5;
    const u32* ip = in + (size_t)e * K2 * N + (size_t)kp0 * N + c0;
    #pragma unroll
    for (int pass = 0; pass < 4; ++pass) {
        int r = pass * 8 + rr;
        uint4 v = *(const uint4*)(ip + (size_t)r * N + c16 * 4);
        tile32[r][c16] = (v.x & 255) | ((v.y & 255) << 8) |
                         ((v.z & 255) << 16) | ((v.w & 255) << 24);
    }
    __syncthreads();

    // phase B: per-col 16 contiguous kp bytes -> dwordx4 store
    int col = tid >> 1, half = tid & 1;
    int cq = col >> 2, sh = (col & 3) * 8;
    uint4 ow; u32* op = &ow.x;
    #pragma unroll
    for (int i = 0; i < 4; ++i) {
        int base = half * 16 + i * 4;
        u32 b0 = (tile32[base + 0][cq] >> sh) & 255;
        u32 b1 = (tile32[base + 1][cq] >> sh) & 255;
        u32 b2 = (tile32[base + 2][cq] >> sh) & 255;
        u32 b3 = (tile32[base + 3][cq] >> sh) & 255;
        op[i] = b0 | (b1 << 8) | (b2 << 16) | (b3 << 24);
    }
    *(uint4*)(out + (size_t)e * N * SP + (size_t)(c0 + col) * SP
              + kp0 + half * 16) = ow;
}

// -------- kernel 2: gather + transpose x -> xcT[k/8][p][8] bf16 --------
__global__ __launch_bounds__(256) void k_xg(const float* __restrict__ x,
                                            const int* __restrict__ ptok,
                                            unsigned short* __restrict__ xcT) {
    int p = blockIdx.x;
    int t = ptok[p];
    int k = threadIdx.x * 8;
    const float* xr = x + (size_t)t * NH + k;
    float4 v0 = *(const float4*)xr;
    float4 v1 = *(const float4*)(xr + 4);
    uint4 w;
    w.x = bfpack2(v0.x, v0.y); w.y = bfpack2(v0.z, v0.w);
    w.z = bfpack2(v1.x, v1.y); w.w = bfpack2(v1.z, v1.w);
    *(uint4*)(xcT + ((size_t)(k >> 3) * NPAIR + p) * 8) = w;
}

// -------- kernel 3: xA_g[p][r], xA_u[p][r] --------
__global__ __launch_bounds__(256) void k_xA(const float* __restrict__ x,
                                            const float* __restrict__ gA,
                                            const float* __restrict__ uA,
                                            const int* __restrict__ ptok,
                                            const int* __restrict__ pexp,
                                            unsigned short* __restrict__ xAg,
                                            unsigned short* __restrict__ xAu) {
    int p = blockIdx.x;
    int t = ptok[p], e = pexp[p];
    int tid = threadIdx.x;
    int r = tid & 15, ch = tid >> 4;
    const float* xr = x + (size_t)t * NH;
    const float* gAr = gA + (size_t)e * NH * NR;
    const float* uAr = uA + (size_t)e * NH * NR;
    float sg = 0.f, su = 0.f;
    for (int j = ch * 128; j < ch * 128 + 128; ++j) {
        float xv = xr[j];
        sg += xv * gAr[j * NR + r];
        su += xv * uAr[j * NR + r];
    }
    __shared__ float red[2][16][16];
    red[0][ch][r] = sg; red[1][ch][r] = su;
    __syncthreads();
    for (int st = 8; st >= 1; st >>= 1) {
        if (ch < st) {
            red[0][ch][r] += red[0][ch + st][r];
            red[1][ch][r] += red[1][ch + st][r];
        }
        __syncthreads();
    }
    if (tid < 16) {
        xAg[p * NR + tid] = (unsigned short)f2bf(red[0][0][tid]);
        xAu[p * NR + tid] = (unsigned short)f2bf(red[1][0][tid]);
    }
}

// -------- kernel 4: gate OR up grouped GEMM (32x32/wave, round-4 config) ----
// Codes: one dwordx4/step/lane from the compact transposed buffer (16
// contiguous bytes = the lane's whole K-step). A: coalesced dwordx4 from xcT.
// Static-named double buffers, unrolled x2; pure-VGPR load deps so the
// compiler inserts exact counted vmcnt. LDS = 1K lut + 4K sclb = 5376 B.
__global__ __launch_bounds__(64, 3) void k_gu(
    const unsigned short* __restrict__ xcT,
    const unsigned char* __restrict__ cgp, const float* __restrict__ gsc,
    const unsigned char* __restrict__ cup, const float* __restrict__ usc,
    const float* __restrict__ gB, const float* __restrict__ uB,
    const unsigned short* __restrict__ xAg, const unsigned short* __restrict__ xAu,
    const int* __restrict__ expert_off,
    unsigned short* __restrict__ gu)
{
    __shared__ u32 lut[256];                  // bf16-pair dequant LUT, 1 KB
    __shared__ float sclb[32][32];            // [step][col], 4 KB

    int lane = threadIdx.x;
    int q = lane >> 5, cw = lane & 31;
    for (int i = lane; i < 256; i += 64)
        lut[i] = bfpack2(NF4_TAB[i & 15], NF4_TAB[(i >> 4) & 15]);

    int e = blockIdx.x;
    int c0 = blockIdx.y * 32;
    int mat = blockIdx.z & 1;
    int rt = blockIdx.z >> 1;                 // row-tile 0..3
    const unsigned char* cp = mat ? cup : cgp;
    const float* scp = mat ? usc : gsc;
    const float* Bp = mat ? uB : gB;
    const unsigned short* xA = mat ? xAu : xAg;

    int off = expert_off[e];
    int cnt = expert_off[e + 1] - off;
    int colg = c0 + cw;

    // stage all 32 per-step scales once per block: sclb[s][col]
    {
        const float* sg = scp + (size_t)e * (NH / NGROUP) * NI + c0;
        #pragma unroll
        for (int g = 0; g < 4; ++g)
            stage16(sg + (size_t)(g * 8 + (lane >> 3)) * NI + ((lane & 7) << 2),
                    &sclb[g * 8][0]);
    }
    WAITV0();                                 // sclb landed

    // per-lane code base: this lane's column, q half (16 B per step)
    const unsigned char* cb = cp + ((size_t)e * NI + colg) * SPG + (q << 4);

    const int NS = NH / 64;                   // 32 K-steps (even)
    for (int s0 = rt * 32; s0 < cnt; s0 += 128) {
        int rr = s0 + cw; if (rr > cnt - 1) rr = cnt - 1;
        int prow = off + rr;

        auto loadC = [&](uint4& c, int s) {   // 16 contiguous code bytes
            c = *(const uint4*)(cb + (s << 5));
        };
        auto loadA = [&](bf16x8* d, int s) {  // 4 coalesced dwordx4 A loads
            #pragma unroll
            for (int ks = 0; ks < 4; ++ks)
                d[ks] = *(const bf16x8*)(xcT +
                            ((size_t)((s << 3) + (q << 2) + ks) * NPAIR + prow) * 8);
        };

        uint4 C0, C1;                         // static-named (unrolled ks)
        bf16x8 Aa[4], Ab[4];
        f32x16 acc;
        #pragma unroll
        for (int i = 0; i < 16; ++i) acc[i] = 0.f;

        auto compute = [&](const uint4& cv, const bf16x8* Ar, float scl) {
            const u32* cd = &cv.x;
            f32x16 t;
            #pragma unroll
            for (int i = 0; i < 16; ++i) t[i] = 0.f;
            #pragma unroll
            for (int ks = 0; ks < 4; ++ks) {
                u32 d = cd[ks];
                uint4 w4;
                w4.x = lut[d & 255];
                w4.y = lut[(d >> 8) & 255];
                w4.z = lut[(d >> 16) & 255];
                w4.w = lut[d >> 24];
                t = MFMA32(Ar[ks], asbf(w4), t, 0, 0, 0);
            }
            #pragma unroll
            for (int i = 0; i < 16; ++i) acc[i] += scl * t[i];
        };

        loadC(C0, 0); loadA(Aa, 0);
        loadC(C1, 1); loadA(Ab, 1);
        for (int s = 0; s < NS; s += 2) {
            compute(C0, Aa, sclb[s][cw]);
            if (s + 2 < NS) { loadC(C0, s + 2); loadA(Aa, s + 2); }
            compute(C1, Ab, sclb[s + 1][cw]);
            if (s + 3 < NS) { loadC(C1, s + 3); loadA(Ab, s + 3); }
        }

        // LoRA extension: += (x.A) . B  (K = 16)
        {
            bf16x8 la = bfzero();
            if (s0 + cw < cnt)
                la = *(const bf16x8*)(xA + (size_t)(off + s0 + cw) * NR + (q << 3));
            const float* Bq = Bp + ((size_t)e * NR + (q << 3)) * NI + colg;
            uint4 w4; u32* wp = &w4.x;
            #pragma unroll
            for (int i = 0; i < 4; ++i)
                wp[i] = bfpack2(Bq[(2 * i) * NI], Bq[(2 * i + 1) * NI]);
            acc = MFMA32(la, asbf(w4), acc, 0, 0, 0);
        }
        // epilogue: store bf16 tile. C row = (reg&3) + 8*(reg>>2) + 4*q
        unsigned short* outb = gu + (size_t)mat * NPAIR * NI;
        #pragma unroll
        for (int reg = 0; reg < 16; ++reg) {
            int rloc = (reg & 3) + 8 * (reg >> 2) + (q << 2);
            if (s0 + rloc < cnt)
                outb[(size_t)(off + s0 + rloc) * NI + colg] =
                    (unsigned short)f2bf(acc[reg]);
        }
    }
}

// -------- kernel 5: h = silu(gate)*up -> hbuf (row-major) + hT (transposed) --
__global__ __launch_bounds__(256) void k_swiglu(const unsigned short* __restrict__ gu,
                                                unsigned short* __restrict__ hbuf,
                                                unsigned short* __restrict__ hT) {
    int i = (blockIdx.x * 256 + threadIdx.x) * 8;
    int p = i >> 10;                          // NI = 1024
    int k0 = i & 1023;
    uint4 gv = *(const uint4*)(gu + i);
    uint4 uv = *(const uint4*)(gu + (size_t)NPAIR * NI + i);
    const u32* gp = &gv.x; const u32* up = &uv.x;
    uint4 hv; u32* hp = &hv.x;
    #pragma unroll
    for (int j = 0; j < 4; ++j) {
        float g0 = bf2f(gp[j] & 0xFFFFu), g1 = bf2f(gp[j] >> 16);
        float u0 = bf2f(up[j] & 0xFFFFu), u1 = bf2f(up[j] >> 16);
        float h0 = g0 * u0 / (1.f + __expf(-g0));
        float h1 = g1 * u1 / (1.f + __expf(-g1));
        hp[j] = bfpack2(h0, h1);
    }
    *(uint4*)(hbuf + i) = hv;
    *(uint4*)(hT + ((size_t)(k0 >> 3) * NPAIR + p) * 8) = hv;
}

// -------- kernel 6: hA[p][r] = h . down_A (row-major hbuf) --------
__global__ __launch_bounds__(256) void k_hA(const unsigned short* __restrict__ hbuf,
                                            const float* __restrict__ dA,
                                            const int* __restrict__ pexp,
                                            unsigned short* __restrict__ hA) {
    int p = blockIdx.x;
    int e = pexp[p];
    int tid = threadIdx.x;
    int r = tid & 15, ch = tid >> 4;
    const unsigned short* hr = hbuf + (size_t)p * NI;
    const float* dAr = dA + (size_t)e * NI * NR;
    float sv = 0.f;
    for (int j = ch * 64; j < ch * 64 + 64; ++j) {
        float hv = bf2f(hr[j]);
        sv += hv * dAr[j * NR + r];
    }
    __shared__ float red[16][16];
    red[ch][r] = sv;
    __syncthreads();
    for (int st = 8; st >= 1; st >>= 1) {
        if (ch < st) red[ch][r] += red[ch + st][r];
        __syncthreads();
    }
    if (tid < 16) hA[p * NR + tid] = (unsigned short)f2bf(red[0][tid]);
}

// -------- kernel 7: down GEMM (round-4 config) + combine ----
// LDS = 1K lut + 2K sclb = 3328 B.
__global__ __launch_bounds__(64, 3) void k_dn(
    const unsigned short* __restrict__ hT,
    const unsigned char* __restrict__ cdp, const float* __restrict__ dsc,
    const float* __restrict__ dB,
    const unsigned short* __restrict__ hA,
    const int* __restrict__ expert_off, const int* __restrict__ ptok,
    const float* __restrict__ pw,
    float* __restrict__ out)
{
    __shared__ u32 lut[256];
    __shared__ float sclb[16][32];

    int lane = threadIdx.x;
    int q = lane >> 5, cw = lane & 31;
    for (int i = lane; i < 256; i += 64)
        lut[i] = bfpack2(NF4_TAB[i & 15], NF4_TAB[(i >> 4) & 15]);

    int e = blockIdx.x;
    int c0 = blockIdx.y * 32;
    int rt = blockIdx.z;                      // 0..3

    int off = expert_off[e];
    int cnt = expert_off[e + 1] - off;
    int colg = c0 + cw;

    {
        const float* sg = dsc + (size_t)e * (NI / NGROUP) * NH + c0;
        #pragma unroll
        for (int g = 0; g < 2; ++g)
            stage16(sg + (size_t)(g * 8 + (lane >> 3)) * NH + ((lane & 7) << 2),
                    &sclb[g * 8][0]);
    }
    WAITV0();

    const unsigned char* cb = cdp + ((size_t)e * NH + colg) * SPD + (q << 4);

    const int NS = NI / 64;                   // 16 K-steps (even)
    for (int s0 = rt * 32; s0 < cnt; s0 += 128) {
        int rr = s0 + cw; if (rr > cnt - 1) rr = cnt - 1;
        int prow = off + rr;

        auto loadC = [&](uint4& c, int s) {
            c = *(const uint4*)(cb + (s << 5));
        };
        auto loadA = [&](bf16x8* d, int s) {
            #pragma unroll
            for (int ks = 0; ks < 4; ++ks)
                d[ks] = *(const bf16x8*)(hT +
                            ((size_t)((s << 3) + (q << 2) + ks) * NPAIR + prow) * 8);
        };

        uint4 C0, C1;
        bf16x8 Aa[4], Ab[4];
        f32x16 acc;
        #pragma unroll
        for (int i = 0; i < 16; ++i) acc[i] = 0.f;

        auto compute = [&](const uint4& cv, const bf16x8* Ar, float scl) {
            const u32* cd = &cv.x;
            f32x16 t;
            #pragma unroll
            for (int i = 0; i < 16; ++i) t[i] = 0.f;
            #pragma unroll
            for (int ks = 0; ks < 4; ++ks) {
                u32 d = cd[ks];
                uint4 w4;
                w4.x = lut[d & 255];
                w4.y = lut[(d >> 8) & 255];
                w4.z = lut[(d >> 16) & 255];
                w4.w = lut[d >> 24];
                t = MFMA32(Ar[ks], asbf(w4), t, 0, 0, 0);
            }
            #pragma unroll
            for (int i = 0; i < 16; ++i) acc[i] += scl * t[i];
        };

        loadC(C0, 0); loadA(Aa, 0);
        loadC(C1, 1); loadA(Ab, 1);
        for (int s = 0; s < NS; s += 2) {
            compute(C0, Aa, sclb[s][cw]);
            if (s + 2 < NS) { loadC(C0, s + 2); loadA(Aa, s + 2); }
            compute(C1, Ab, sclb[s + 1][cw]);
            if (s + 3 < NS) { loadC(C1, s + 3); loadA(Ab, s + 3); }
        }

        // LoRA extension: += (h.down_A) . down_B (K = 16)
        {
            bf16x8 la = bfzero();
            if (s0 + cw < cnt)
                la = *(const bf16x8*)(hA + (size_t)(off + s0 + cw) * NR + (q << 3));
            const float* Bq = dB + ((size_t)e * NR + (q << 3)) * NH + colg;
            uint4 w4; u32* wp = &w4.x;
            #pragma unroll
            for (int i = 0; i < 4; ++i)
                wp[i] = bfpack2(Bq[(2 * i) * NH], Bq[(2 * i + 1) * NH]);
            acc = MFMA32(la, asbf(w4), acc, 0, 0, 0);
        }
        // epilogue: weighted atomic combine
        #pragma unroll
        for (int reg = 0; reg < 16; ++reg) {
            int rloc = (reg & 3) + 8 * (reg >> 2) + (q << 2);
            if (s0 + rloc < cnt) {
                int p = off + s0 + rloc;
                atomicAdd(&out[(size_t)ptok[p] * NH + colg], acc[reg] * pw[p]);
            }
        }
    }
}

extern "C" void kernel_launch(void* const* d_in, const int* in_sizes, int n_in,
                              void* d_out, int out_size, void* d_ws,
                              size_t ws_size, hipStream_t stream) {
    const float* x = (const float*)d_in[0];
    const int* topk_idx = (const int*)d_in[1];
    const float* topk_w = (const float*)d_in[2];
    const int* gate_packed = (const int*)d_in[3];
    const float* gate_scales = (const float*)d_in[4];
    const int* up_packed = (const int*)d_in[5];
    const float* up_scales = (const float*)d_in[6];
    const int* down_packed = (const int*)d_in[7];
    const float* down_scales = (const float*)d_in[8];
    const float* gate_A = (const float*)d_in[9];
    const float* gate_B = (const float*)d_in[10];
    const float* up_A = (const float*)d_in[11];
    const float* up_B = (const float*)d_in[12];
    const float* down_A = (const float*)d_in[13];
    const float* down_B = (const float*)d_in[14];
    float* out = (float*)d_out;

    char* ws = (char*)d_ws;
    int* expert_off = (int*)(ws + OFF_EXPOFF);
    int* ptok = (int*)(ws + OFF_TOK);
    int* pexp = (int*)(ws + OFF_EXP);
    float* pw = (float*)(ws + OFF_W);
    unsigned short* xAg = (unsigned short*)(ws + OFF_XAG);
    unsigned short* xAu = (unsigned short*)(ws + OFF_XAU);
    unsigned short* hA = (unsigned short*)(ws + OFF_HA);
    unsigned short* xcT = (unsigned short*)(ws + OFF_XCT);
    unsigned short* gu = (unsigned short*)(ws + OFF_GU);
    unsigned short* hbuf = (unsigned short*)(ws + OFF_HBUF);
    unsigned short* hT = (unsigned short*)(ws + OFF_HT);
    unsigned char* cg = (unsigned char*)(ws + OFF_CG);
    unsigned char* cu = (unsigned char*)(ws + OFF_CU);
    unsigned char* cd = (unsigned char*)(ws + OFF_CD);

    hipMemsetAsync(d_out, 0, (size_t)NT * NH * sizeof(float), stream);

    // weight compact+transpose prepass (all 3 matrices) + routing, one launch
    k_cmp3<<<dim3(16, 32, 25), 256, 0, stream>>>(
        (const u32*)gate_packed, (const u32*)up_packed, (const u32*)down_packed,
        cg, cu, cd, topk_idx, topk_w, expert_off, ptok, pexp, pw);

    k_xg<<<NPAIR, 256, 0, stream>>>(x, ptok, xcT);
    k_xA<<<NPAIR, 256, 0, stream>>>(x, gate_A, up_A, ptok, pexp, xAg, xAu);
    k_gu<<<dim3(NE, NI / 32, 8), 64, 0, stream>>>(
        xcT, cg, gate_scales, cu, up_scales, gate_B, up_B,
        xAg, xAu, expert_off, gu);
    k_swiglu<<<(NPAIR * NI) / (256 * 8), 256, 0, stream>>>(gu, hbuf, hT);
    k_hA<<<NPAIR, 256, 0, stream>>>(hbuf, down_A, pexp, hA);
    k_dn<<<dim3(NE, NH / 32, 4), 64, 0, stream>>>(
        hT, cd, down_scales, down_B, hA, expert_off, ptok, pw, out);
}